// Round 19
// baseline (851.662 us; speedup 1.0000x reference)
//
#include <hip/hip_runtime.h>

#define Hdim 128
#define Fdim 16
#define Ddim 16
#define Tdim 8
#define Bdim 2
#define TC 4          // timesteps per chunk (2 chunks)
#define TSL 2         // pull t-slices (t in {2s, 2s+1} per slice)

typedef _Float16 h2 __attribute__((ext_vector_type(2)));
typedef _Float16 h4 __attribute__((ext_vector_type(4)));
typedef _Float16 half8 __attribute__((ext_vector_type(8)));
typedef float floatx4 __attribute__((ext_vector_type(4)));

__device__ __forceinline__ float sigm(float u) { return 1.f / (1.f + __expf(-u)); }

// chunk row layout (fp32 x, fp16 agg, fp16 gi): flat row = (n*TC+tin)*Bdim+b.
// fp16 gather shadow xp is BATCH-PAIRED: elem((n*TC+tin)*128 + ch)*2 + b.

// ---------------- encoder: one thread computes BOTH batches -----------------
__global__ __launch_bounds__(256) void enc_kernel(
    const float* __restrict__ xseq, const float* __restrict__ enc_w,
    const float* __restrict__ enc_b, float* __restrict__ x,
    _Float16* __restrict__ xp, int N, int t0)
{
  int gid = blockIdx.x * 256 + threadIdx.x;
  int ntr = gid >> 5;          // n*TC + tin
  int q   = gid & 31;          // channel quad
  if (ntr >= N * TC) return;
  int tin = ntr & (TC - 1);
  int n   = ntr >> 2;          // TC == 4
  const float* xs0 = xseq + (((size_t)(t0 + tin)) * N + n) * Fdim;
  const float* xs1 = xs0 + (size_t)Tdim * N * Fdim;
  float4 bq = ((const float4*)enc_b)[q];
  float4 a0 = bq, a1 = bq;
#pragma unroll
  for (int f = 0; f < Fdim; ++f) {
    float s0 = xs0[f], s1 = xs1[f];
    float4 w = ((const float4*)enc_w)[f * (Hdim / 4) + q];
    a0.x += s0 * w.x; a0.y += s0 * w.y; a0.z += s0 * w.z; a0.w += s0 * w.w;
    a1.x += s1 * w.x; a1.y += s1 * w.y; a1.z += s1 * w.z; a1.w += s1 * w.w;
  }
  ((float4*)x)[((size_t)ntr * 2 + 0) * 32 + q] = a0;
  ((float4*)x)[((size_t)ntr * 2 + 1) * 32 + q] = a1;
  half8 hv = { (_Float16)a0.x, (_Float16)a1.x, (_Float16)a0.y, (_Float16)a1.y,
               (_Float16)a0.z, (_Float16)a1.z, (_Float16)a0.w, (_Float16)a1.w };
  *(half8*)(xp + ((size_t)ntr * Hdim + q * 4) * 2) = hv;
}

// ---------------- CSR build: count, scan, fill ------------------------------
__global__ __launch_bounds__(256) void count_kernel(
    const int* __restrict__ ei, int* __restrict__ cnt, int E)
{
  int e = blockIdx.x * 256 + threadIdx.x;
  if (e < E) atomicAdd(&cnt[ei[E + e]], 1);
}

__global__ __launch_bounds__(1024) void scan_kernel(
    const int* __restrict__ cnt, int* __restrict__ off, int N)
{
  __shared__ int part[1024];
  int tid = threadIdx.x;
  int per = (N + 1023) / 1024;
  int base = tid * per;
  int s = 0;
  for (int i = 0; i < per; ++i) { int idx = base + i; if (idx < N) s += cnt[idx]; }
  part[tid] = s;
  __syncthreads();
  for (int d = 1; d < 1024; d <<= 1) {
    int v = (tid >= d) ? part[tid - d] : 0;
    __syncthreads();
    part[tid] += v;
    __syncthreads();
  }
  int run = (tid == 0) ? 0 : part[tid - 1];
  for (int i = 0; i < per; ++i) {
    int idx = base + i;
    if (idx < N) { off[idx] = run; run += cnt[idx]; }
  }
  if (tid == 1023) off[N] = part[1023];
}

__global__ __launch_bounds__(256) void fill_kernel(
    const int* __restrict__ ei, int* __restrict__ off,
    int* __restrict__ eids, int* __restrict__ src_csr, int E)
{
  int e = blockIdx.x * 256 + threadIdx.x;
  if (e < E) {
    int d = ei[E + e];
    int pos = atomicAdd(&off[d], 1);
    eids[pos] = e;
    src_csr[pos] = ei[e];
  }
}

// ---- pack ALL weights (MLP m1w/m2w x2 layers + GRU wih|whh) in one kernel --
__global__ __launch_bounds__(256) void pack_all_kernel(
    const float* __restrict__ m1w, const float* __restrict__ m2w,
    const float* __restrict__ wih, const float* __restrict__ whh,
    _Float16* __restrict__ wpk, _Float16* __restrict__ wgru)
{
  int t = blockIdx.x * 256 + threadIdx.x;
  if (t < 8192) {                 // MLP: which = 2*l + is_m2
    int u = t & 2047, which = t >> 11;
    const float* W = ((which & 1) ? m2w : m1w) + (size_t)(which >> 1) * Hdim * Hdim;
    _Float16* Wp = wpk + (size_t)which * 16384;
    int lane = u & 63, ks = (u >> 6) & 3, nt = u >> 8;
    int col = nt * 16 + (lane & 15);
    int k0  = ks * 32 + (lane >> 4) * 8;
    half8 o;
#pragma unroll
    for (int j = 0; j < 8; ++j) o[j] = (_Float16)W[(k0 + j) * Hdim + col];
    *(half8*)(Wp + (size_t)u * 8) = o;
  } else if (t < 8192 + 12288) {  // GRU
    int u2 = t - 8192;
    int m = u2 >= 6144;
    int u = m ? u2 - 6144 : u2;
    int lane = u & 63, ks = (u >> 6) & 3, nt = u >> 8;
    int col = nt * 16 + (lane & 15);
    int k0  = ks * 32 + (lane >> 4) * 8;
    const float* W = m ? whh : wih;
    half8 o;
#pragma unroll
    for (int j = 0; j < 8; ++j) o[j] = (_Float16)W[(k0 + j) * 384 + col];
    *(half8*)(wgru + (size_t)u2 * 8) = o;
  }
}

// ---- pull: one wave per (node, t-slice); 2-edge unrolled -------------------
// blockIdx.y = slice (t in {2s,2s+1}): halves the per-edge gather (1KB) and,
// since slices are dispatched y-major, the per-XCD xp working set drops from
// 20MB to 10MB -> L2-resident gathers. Bit-identical: each acc[t][b] sums the
// same edge terms in the same order; only the wave->(t-slice) map changed.
__global__ __launch_bounds__(256) void pull_kernel(
    const float* __restrict__ x, const _Float16* __restrict__ xp,
    _Float16* __restrict__ aggh,
    const int* __restrict__ src_csr, const int* __restrict__ off,
    const int* __restrict__ eids, const float* __restrict__ attr,
    const float* __restrict__ eW_l, const float* __restrict__ eb_l,
    int N)
{
  int node = __builtin_amdgcn_readfirstlane(
      blockIdx.x * 4 + (threadIdx.x >> 6));
  if (node >= N) return;
  int slice = blockIdx.y;      // t = slice*2 + tt
  int c = threadIdx.x & 63;    // lane owns channels {2c, 2c+1}

  float2 w[16];
#pragma unroll
  for (int d = 0; d < 16; ++d) w[d] = ((const float2*)eW_l)[d * 64 + c];
  float2 bq = ((const float2*)eb_l)[c];

  int start = (node == 0) ? 0 : off[node - 1];
  int end   = off[node];

  float2 acc[2][Bdim];
#pragma unroll
  for (int tt = 0; tt < 2; ++tt)
#pragma unroll
    for (int b = 0; b < Bdim; ++b) { acc[tt][b].x = 0.f; acc[tt][b].y = 0.f; }

  int sl128 = slice * 128;     // slice base in h4 units (2 t * 64 h4)

  int i = start;
  for (; i + 2 <= end; i += 2) {          // two independent edges in flight
    int sA = src_csr[i], sB = src_csr[i + 1];
    int eA = eids[i],    eB = eids[i + 1];
    const float* avA = attr + (size_t)eA * 16;
    const float* avB = attr + (size_t)eB * 16;
    float2 emA = bq, emB = bq;
#pragma unroll
    for (int d = 0; d < 16; ++d) {
      float aA = avA[d], aB = avB[d];      // s_loads (uniform)
      emA.x += aA * w[d].x; emA.y += aA * w[d].y;
      emB.x += aB * w[d].x; emB.y += aB * w[d].y;
    }
    const h4* xsA = (const h4*)(xp + (size_t)sA * (TC * Bdim * Hdim)) + sl128;
    const h4* xsB = (const h4*)(xp + (size_t)sB * (TC * Bdim * Hdim)) + sl128;
#pragma unroll
    for (int tt = 0; tt < 2; ++tt) {
      h4 vA = xsA[tt * 64 + c];
      h4 vB = xsB[tt * 64 + c];
      acc[tt][0].x += fmaxf((float)vA.x + emA.x, 0.f);
      acc[tt][1].x += fmaxf((float)vA.y + emA.x, 0.f);
      acc[tt][0].y += fmaxf((float)vA.z + emA.y, 0.f);
      acc[tt][1].y += fmaxf((float)vA.w + emA.y, 0.f);
      acc[tt][0].x += fmaxf((float)vB.x + emB.x, 0.f);
      acc[tt][1].x += fmaxf((float)vB.y + emB.x, 0.f);
      acc[tt][0].y += fmaxf((float)vB.z + emB.y, 0.f);
      acc[tt][1].y += fmaxf((float)vB.w + emB.y, 0.f);
    }
  }
  if (i < end) {                           // odd tail edge
    int sA = src_csr[i], eA = eids[i];
    const float* avA = attr + (size_t)eA * 16;
    float2 emA = bq;
#pragma unroll
    for (int d = 0; d < 16; ++d) {
      float aA = avA[d];
      emA.x += aA * w[d].x; emA.y += aA * w[d].y;
    }
    const h4* xsA = (const h4*)(xp + (size_t)sA * (TC * Bdim * Hdim)) + sl128;
#pragma unroll
    for (int tt = 0; tt < 2; ++tt) {
      h4 vA = xsA[tt * 64 + c];
      acc[tt][0].x += fmaxf((float)vA.x + emA.x, 0.f);
      acc[tt][1].x += fmaxf((float)vA.y + emA.x, 0.f);
      acc[tt][0].y += fmaxf((float)vA.z + emA.y, 0.f);
      acc[tt][1].y += fmaxf((float)vA.w + emA.y, 0.f);
    }
  }

  const float2* x2 = (const float2*)x;
  const float2* xn = x2 + (size_t)node * (TC * Bdim * 64);
  _Float16* an = aggh + (size_t)node * (TC * Bdim * Hdim);
#pragma unroll
  for (int tt = 0; tt < 2; ++tt)
#pragma unroll
    for (int b = 0; b < Bdim; ++b) {
      int tb = (slice * 2 + tt) * Bdim + b;
      float2 s = xn[tb * 64 + c];          // self term, exact fp32
      h2 o = { (_Float16)(acc[tt][b].x + s.x), (_Float16)(acc[tt][b].y + s.y) };
      *(h2*)(an + tb * Hdim + 2 * c) = o;
    }
}

// ------- MLP via MFMA + optional fused gi (x@wih+bias) for the last layer ---
// ONE WAVE PER BLOCK (no barriers anywhere). mid fp16 (bit-identical).
// gi written with DIRECT stores (r15+r17 both showed LDS staging loses).
template<int DO_GI>
__global__ __launch_bounds__(64) void mlp_mfma_kernel(
    float* __restrict__ x, _Float16* __restrict__ xp,
    const _Float16* __restrict__ aggh,
    const _Float16* __restrict__ w1p, const _Float16* __restrict__ w2p,
    const float* __restrict__ m1b, const float* __restrict__ m2b,
    const float* __restrict__ lng, const float* __restrict__ lnb,
    const _Float16* __restrict__ wip, const float* __restrict__ bih,
    const float* __restrict__ bhh, _Float16* __restrict__ gi)
{
  __shared__ _Float16 midw[16][136];
  int lane = threadIdx.x;
  int row0 = blockIdx.x * 16;
  int mrow = lane & 15;
  int kgrp = lane >> 4;

  // A frags straight from fp16 agg (contiguous 16B loads)
  half8 afrag[4];
  const _Float16* abase = aggh + (size_t)(row0 + mrow) * Hdim + kgrp * 8;
#pragma unroll
  for (int ks = 0; ks < 4; ++ks)
    afrag[ks] = *(const half8*)(abase + ks * 32);

#pragma unroll
  for (int nt = 0; nt < 8; ++nt) {
    floatx4 acc = {0.f, 0.f, 0.f, 0.f};
#pragma unroll
    for (int ks = 0; ks < 4; ++ks) {
      half8 b = *(const half8*)(w1p + ((size_t)(nt * 4 + ks) * 64 + lane) * 8);
      acc = __builtin_amdgcn_mfma_f32_16x16x32_f16(afrag[ks], b, acc, 0, 0, 0);
    }
    int col = nt * 16 + mrow;
    float bv = m1b[col];
#pragma unroll
    for (int r = 0; r < 4; ++r)
      midw[kgrp * 4 + r][col] = (_Float16)fmaxf(acc[r] + bv, 0.f);
  }
  // single wave: compiler's lgkmcnt ordering covers write->read

  half8 afrag2[4];
#pragma unroll
  for (int ks = 0; ks < 4; ++ks)
    afrag2[ks] = *(const half8*)(&midw[mrow][kgrp * 8 + ks * 32]);

  floatx4 acc2[8];
#pragma unroll
  for (int nt = 0; nt < 8; ++nt) {
    floatx4 acc = {0.f, 0.f, 0.f, 0.f};
#pragma unroll
    for (int ks = 0; ks < 4; ++ks) {
      half8 b = *(const half8*)(w2p + ((size_t)(nt * 4 + ks) * 64 + lane) * 8);
      acc = __builtin_amdgcn_mfma_f32_16x16x32_f16(afrag2[ks], b, acc, 0, 0, 0);
    }
    float bv = m2b[nt * 16 + mrow];
#pragma unroll
    for (int r = 0; r < 4; ++r) acc[r] += bv;
    acc2[nt] = acc;
  }

  float s1[4] = {0.f, 0.f, 0.f, 0.f}, s2[4] = {0.f, 0.f, 0.f, 0.f};
#pragma unroll
  for (int nt = 0; nt < 8; ++nt)
#pragma unroll
    for (int r = 0; r < 4; ++r) {
      float v = acc2[nt][r];
      s1[r] += v; s2[r] += v * v;
    }
#pragma unroll
  for (int r = 0; r < 4; ++r) {
#pragma unroll
    for (int o = 1; o < 16; o <<= 1) {
      s1[r] += __shfl_xor(s1[r], o);
      s2[r] += __shfl_xor(s2[r], o);
    }
  }
  float mu[4], rstd[4];
#pragma unroll
  for (int r = 0; r < 4; ++r) {
    mu[r] = s1[r] * (1.f / Hdim);
    float var = fmaxf(s2[r] * (1.f / Hdim) - mu[r] * mu[r], 0.f);
    rstd[r] = rsqrtf(var + 1e-5f);
  }

#pragma unroll
  for (int nt = 0; nt < 8; ++nt) {
    int col = nt * 16 + mrow;
    float g = lng[col], bb = lnb[col];
#pragma unroll
    for (int r = 0; r < 4; ++r) {
      int row = row0 + kgrp * 4 + r;
      float y = (acc2[nt][r] - mu[r]) * rstd[r] * g + bb;
      float xr = x[(size_t)row * Hdim + col];
      float o = fmaxf(y, 0.f) + xr;
      x[(size_t)row * Hdim + col] = o;
      xp[((size_t)(row >> 1) * Hdim + col) * 2 + (row & 1)] = (_Float16)o;
      if (DO_GI) midw[kgrp * 4 + r][col] = (_Float16)o;  // stage new x for gi
    }
  }

  if (DO_GI) {
    // gi A-frags from the staged fp16 new-x (same rounding as before)
    half8 ax[4];
#pragma unroll
    for (int ks = 0; ks < 4; ++ks)
      ax[ks] = *(const half8*)(&midw[mrow][kgrp * 8 + ks * 32]);
#pragma unroll
    for (int nt = 0; nt < 24; ++nt) {
      int col = nt * 16 + mrow;
      float bv = bih[col] + ((nt < 16) ? bhh[col] : 0.f);
      floatx4 a = {bv, bv, bv, bv};
#pragma unroll
      for (int ks = 0; ks < 4; ++ks) {
        half8 bf = *(const half8*)(wip + ((size_t)(nt * 4 + ks) * 64 + lane) * 8);
        a = __builtin_amdgcn_mfma_f32_16x16x32_f16(ax[ks], bf, a, 0, 0, 0);
      }
#pragma unroll
      for (int r = 0; r < 4; ++r)
        gi[(size_t)(row0 + kgrp * 4 + r) * 384 + col] = (_Float16)a[r];
    }
  }
}

// ---- fused 4-step GRU v3: column-split across 4 waves ----------------------
__global__ __launch_bounds__(256) void gru4_kernel(
    float* __restrict__ hg, const _Float16* __restrict__ whp,
    const float* __restrict__ bhh, const _Float16* __restrict__ gi, int N)
{
  __shared__ _Float16 hl[16][136];
  int wv = threadIdx.x >> 6, lane = threadIdx.x & 63;
  int row0 = blockIdx.x * 16;
  int mcol = lane & 15, kgrp = lane >> 4;
  int sr0 = row0 + kgrp * 4;

  float hreg[2][4];
#pragma unroll
  for (int j = 0; j < 2; ++j) {
    int col = (wv * 2 + j) * 16 + mcol;
#pragma unroll
    for (int r = 0; r < 4; ++r) {
      float v = hg[(size_t)(sr0 + r) * Hdim + col];
      hreg[j][r] = v;
      hl[kgrp * 4 + r][col] = (_Float16)v;
    }
  }
  __syncthreads();

  float bn[2];
#pragma unroll
  for (int j = 0; j < 2; ++j) bn[j] = bhh[256 + (wv * 2 + j) * 16 + mcol];

  for (int tin = 0; tin < TC; ++tin) {
    half8 ah[4];
#pragma unroll
    for (int ks = 0; ks < 4; ++ks)
      ah[ks] = *(const half8*)(&hl[mcol][ks * 32 + kgrp * 8]);

    int cr[4];
#pragma unroll
    for (int r = 0; r < 4; ++r) {
      int sr = sr0 + r;
      int b = sr >= N;
      int n = sr - b * N;
      cr[r] = (n * TC + tin) * Bdim + b;
    }

    floatx4 ar[2], az[2], ahn[2];
    float gn[2][4];
#pragma unroll
    for (int j = 0; j < 2; ++j) {
      int col = (wv * 2 + j) * 16 + mcol;
#pragma unroll
      for (int r = 0; r < 4; ++r) {
        ar[j][r] = (float)gi[(size_t)cr[r] * 384 + col];
        az[j][r] = (float)gi[(size_t)cr[r] * 384 + 128 + col];
        gn[j][r] = (float)gi[(size_t)cr[r] * 384 + 256 + col];
      }
    }
#pragma unroll
    for (int j = 0; j < 2; ++j) {
      int nt = wv * 2 + j;
      floatx4 an4 = {bn[j], bn[j], bn[j], bn[j]};
#pragma unroll
      for (int ks = 0; ks < 4; ++ks) {
        half8 bfr = *(const half8*)(whp + ((size_t)(nt * 4 + ks) * 64 + lane) * 8);
        ar[j] = __builtin_amdgcn_mfma_f32_16x16x32_f16(ah[ks], bfr, ar[j], 0, 0, 0);
        half8 bfz = *(const half8*)(whp + ((size_t)((8 + nt) * 4 + ks) * 64 + lane) * 8);
        az[j] = __builtin_amdgcn_mfma_f32_16x16x32_f16(ah[ks], bfz, az[j], 0, 0, 0);
        half8 bfn = *(const half8*)(whp + ((size_t)((16 + nt) * 4 + ks) * 64 + lane) * 8);
        an4 = __builtin_amdgcn_mfma_f32_16x16x32_f16(ah[ks], bfn, an4, 0, 0, 0);
      }
      ahn[j] = an4;
    }

    __syncthreads();   // all waves' ds_reads of hl complete before overwrite
#pragma unroll
    for (int j = 0; j < 2; ++j) {
      int col = (wv * 2 + j) * 16 + mcol;
#pragma unroll
      for (int r = 0; r < 4; ++r) {
        float rg = sigm(ar[j][r]);
        float zg = sigm(az[j][r]);
        float u = gn[j][r] + rg * ahn[j][r];
        float ng = 2.f / (1.f + __expf(-2.f * u)) - 1.f;   // tanh
        float hnew = (1.f - zg) * ng + zg * hreg[j][r];
        hreg[j][r] = hnew;
        hl[kgrp * 4 + r][col] = (_Float16)hnew;
      }
    }
    __syncthreads();
  }

#pragma unroll
  for (int j = 0; j < 2; ++j) {
    int col = (wv * 2 + j) * 16 + mcol;
#pragma unroll
    for (int r = 0; r < 4; ++r)
      hg[(size_t)(sr0 + r) * Hdim + col] = hreg[j][r];
  }
}

// ---------------- head: out[row] = dot(h[row], head_w) + head_b -------------
__global__ __launch_bounds__(128) void head_kernel(
    const float* __restrict__ hg, const float* __restrict__ hw,
    const float* __restrict__ hb, float* __restrict__ out)
{
  int row = blockIdx.x;
  int j = threadIdx.x;
  __shared__ float red[2];
  float v = hg[(size_t)row * Hdim + j] * hw[j];
#pragma unroll
  for (int off = 32; off >= 1; off >>= 1) v += __shfl_xor(v, off);
  int wid = j >> 6, lane = j & 63;
  if (lane == 0) red[wid] = v;
  __syncthreads();
  if (j == 0) out[row] = red[0] + red[1] + hb[0];
}

extern "C" void kernel_launch(void* const* d_in, const int* in_sizes, int n_in,
                              void* d_out, int out_size, void* d_ws, size_t ws_size,
                              hipStream_t stream)
{
  const float* xseq  = (const float*)d_in[0];
  const int*   ei    = (const int*)d_in[1];
  const float* attr  = (const float*)d_in[2];
  const float* enc_w = (const float*)d_in[3];
  const float* enc_b = (const float*)d_in[4];
  const float* eW    = (const float*)d_in[5];
  const float* eb    = (const float*)d_in[6];
  const float* m1w   = (const float*)d_in[7];
  const float* m1b   = (const float*)d_in[8];
  const float* m2w   = (const float*)d_in[9];
  const float* m2b   = (const float*)d_in[10];
  const float* lng   = (const float*)d_in[11];
  const float* lnb   = (const float*)d_in[12];
  const float* wih   = (const float*)d_in[13];
  const float* whh   = (const float*)d_in[14];
  const float* bih   = (const float*)d_in[15];
  const float* bhh   = (const float*)d_in[16];
  const float* hw    = (const float*)d_in[17];
  const float* hb    = (const float*)d_in[18];

  int E = in_sizes[1] / 2;
  int N = in_sizes[0] / (Bdim * Tdim * Fdim);
  int rowsState = Bdim * N;                    // 20000
  int rowsC = TC * Bdim * N;                   // 80000
  size_t SC = (size_t)rowsC * Hdim;
  size_t SS = (size_t)rowsState * Hdim;

  float*     x    = (float*)d_ws;              // SC floats
  float*     hgb  = x + SC;                    // SS floats
  _Float16*  aggh = (_Float16*)(hgb + SS);     // fp16 agg, SC halfs
  _Float16*  xp   = aggh + SC;                 // paired fp16 shadow, SC halfs
  _Float16*  wpk  = xp + SC;                   // MLP packed: 4 * 16384 halfs
  _Float16*  wgru = wpk + 4 * 16384;           // GRU packed: 12288*8 halfs
  _Float16*  gi   = wgru + 98304;              // [rowsC][384] fp16
  int*   cnt  = (int*)(gi + (size_t)rowsC * 384);
  int*   off  = cnt + N;
  int*   eids = off + (N + 1);
  int*   src_csr = eids + E;

  hipMemsetAsync(hgb, 0, SS * sizeof(float), stream);
  hipMemsetAsync(cnt, 0, N * sizeof(int), stream);

  int eBlocks    = (E + 255) / 256;
  int encBlocks  = (N * TC * 32 + 255) / 256;  // 5000
  int mlpBlocks  = rowsC / 16;                 // 5000 (64-thread blocks)
  int gruBlocks  = rowsState / 16;             // 1250
  int pullBlocks = (N + 3) / 4;                // 2500 per slice

  count_kernel<<<eBlocks, 256, 0, stream>>>(ei, cnt, E);
  scan_kernel<<<1, 1024, 0, stream>>>(cnt, off, N);
  fill_kernel<<<eBlocks, 256, 0, stream>>>(ei, off, eids, src_csr, E);
  pack_all_kernel<<<80, 256, 0, stream>>>(m1w, m2w, wih, whh, wpk, wgru);

  for (int c = 0; c < Tdim / TC; ++c) {
    enc_kernel<<<encBlocks, 256, 0, stream>>>(xseq, enc_w, enc_b, x, xp, N, c * TC);
    for (int l = 0; l < 2; ++l) {
      pull_kernel<<<dim3(pullBlocks, TSL), 256, 0, stream>>>(
          x, xp, aggh, src_csr, off, eids, attr,
          eW + (size_t)l * Ddim * Hdim, eb + (size_t)l * Hdim, N);
      if (l == 0) {
        mlp_mfma_kernel<0><<<mlpBlocks, 64, 0, stream>>>(
            x, xp, aggh,
            wpk + (size_t)0 * 16384, wpk + (size_t)1 * 16384,
            m1b, m2b, lng, lnb, nullptr, nullptr, nullptr, nullptr);
      } else {
        mlp_mfma_kernel<1><<<mlpBlocks, 64, 0, stream>>>(
            x, xp, aggh,
            wpk + (size_t)2 * 16384, wpk + (size_t)3 * 16384,
            m1b + Hdim, m2b + Hdim, lng + Hdim, lnb + Hdim,
            wgru, bih, bhh, gi);
      }
    }
    gru4_kernel<<<gruBlocks, 256, 0, stream>>>(hgb, wgru + 6144 * 8, bhh, gi, N);
  }
  head_kernel<<<rowsState, 128, 0, stream>>>(hgb, hw, hb, (float*)d_out);
}

// Round 20
// 714.161 us; speedup vs baseline: 1.1925x; 1.1925x over previous
//
#include <hip/hip_runtime.h>

#define Hdim 128
#define Fdim 16
#define Ddim 16
#define Tdim 8
#define Bdim 2
#define TC 4          // timesteps per chunk (2 chunks)

typedef _Float16 h2 __attribute__((ext_vector_type(2)));
typedef _Float16 h4 __attribute__((ext_vector_type(4)));
typedef _Float16 half8 __attribute__((ext_vector_type(8)));
typedef float floatx4 __attribute__((ext_vector_type(4)));

__device__ __forceinline__ float sigm(float u) { return 1.f / (1.f + __expf(-u)); }

// chunk row layout (fp32 x, fp16 agg, fp16 gi): flat row = (n*TC+tin)*Bdim+b.
// fp16 gather shadow xp is BATCH-PAIRED: elem((n*TC+tin)*128 + ch)*2 + b.

// ---------------- encoder: one thread computes BOTH batches -----------------
__global__ __launch_bounds__(256) void enc_kernel(
    const float* __restrict__ xseq, const float* __restrict__ enc_w,
    const float* __restrict__ enc_b, float* __restrict__ x,
    _Float16* __restrict__ xp, int N, int t0)
{
  int gid = blockIdx.x * 256 + threadIdx.x;
  int ntr = gid >> 5;          // n*TC + tin
  int q   = gid & 31;          // channel quad
  if (ntr >= N * TC) return;
  int tin = ntr & (TC - 1);
  int n   = ntr >> 2;          // TC == 4
  const float* xs0 = xseq + (((size_t)(t0 + tin)) * N + n) * Fdim;
  const float* xs1 = xs0 + (size_t)Tdim * N * Fdim;
  float4 bq = ((const float4*)enc_b)[q];
  float4 a0 = bq, a1 = bq;
#pragma unroll
  for (int f = 0; f < Fdim; ++f) {
    float s0 = xs0[f], s1 = xs1[f];
    float4 w = ((const float4*)enc_w)[f * (Hdim / 4) + q];
    a0.x += s0 * w.x; a0.y += s0 * w.y; a0.z += s0 * w.z; a0.w += s0 * w.w;
    a1.x += s1 * w.x; a1.y += s1 * w.y; a1.z += s1 * w.z; a1.w += s1 * w.w;
  }
  ((float4*)x)[((size_t)ntr * 2 + 0) * 32 + q] = a0;
  ((float4*)x)[((size_t)ntr * 2 + 1) * 32 + q] = a1;
  half8 hv = { (_Float16)a0.x, (_Float16)a1.x, (_Float16)a0.y, (_Float16)a1.y,
               (_Float16)a0.z, (_Float16)a1.z, (_Float16)a0.w, (_Float16)a1.w };
  *(half8*)(xp + ((size_t)ntr * Hdim + q * 4) * 2) = hv;
}

// ---------------- CSR build: count, scan, fill ------------------------------
__global__ __launch_bounds__(256) void count_kernel(
    const int* __restrict__ ei, int* __restrict__ cnt, int E)
{
  int e = blockIdx.x * 256 + threadIdx.x;
  if (e < E) atomicAdd(&cnt[ei[E + e]], 1);
}

__global__ __launch_bounds__(1024) void scan_kernel(
    const int* __restrict__ cnt, int* __restrict__ off, int N)
{
  __shared__ int part[1024];
  int tid = threadIdx.x;
  int per = (N + 1023) / 1024;
  int base = tid * per;
  int s = 0;
  for (int i = 0; i < per; ++i) { int idx = base + i; if (idx < N) s += cnt[idx]; }
  part[tid] = s;
  __syncthreads();
  for (int d = 1; d < 1024; d <<= 1) {
    int v = (tid >= d) ? part[tid - d] : 0;
    __syncthreads();
    part[tid] += v;
    __syncthreads();
  }
  int run = (tid == 0) ? 0 : part[tid - 1];
  for (int i = 0; i < per; ++i) {
    int idx = base + i;
    if (idx < N) { off[idx] = run; run += cnt[idx]; }
  }
  if (tid == 1023) off[N] = part[1023];
}

__global__ __launch_bounds__(256) void fill_kernel(
    const int* __restrict__ ei, int* __restrict__ off,
    int* __restrict__ eids, int* __restrict__ src_csr, int E)
{
  int e = blockIdx.x * 256 + threadIdx.x;
  if (e < E) {
    int d = ei[E + e];
    int pos = atomicAdd(&off[d], 1);
    eids[pos] = e;
    src_csr[pos] = ei[e];
  }
}

// ---- pack ALL weights (MLP m1w/m2w x2 layers + GRU wih|whh) in one kernel --
__global__ __launch_bounds__(256) void pack_all_kernel(
    const float* __restrict__ m1w, const float* __restrict__ m2w,
    const float* __restrict__ wih, const float* __restrict__ whh,
    _Float16* __restrict__ wpk, _Float16* __restrict__ wgru)
{
  int t = blockIdx.x * 256 + threadIdx.x;
  if (t < 8192) {                 // MLP: which = 2*l + is_m2
    int u = t & 2047, which = t >> 11;
    const float* W = ((which & 1) ? m2w : m1w) + (size_t)(which >> 1) * Hdim * Hdim;
    _Float16* Wp = wpk + (size_t)which * 16384;
    int lane = u & 63, ks = (u >> 6) & 3, nt = u >> 8;
    int col = nt * 16 + (lane & 15);
    int k0  = ks * 32 + (lane >> 4) * 8;
    half8 o;
#pragma unroll
    for (int j = 0; j < 8; ++j) o[j] = (_Float16)W[(k0 + j) * Hdim + col];
    *(half8*)(Wp + (size_t)u * 8) = o;
  } else if (t < 8192 + 12288) {  // GRU
    int u2 = t - 8192;
    int m = u2 >= 6144;
    int u = m ? u2 - 6144 : u2;
    int lane = u & 63, ks = (u >> 6) & 3, nt = u >> 8;
    int col = nt * 16 + (lane & 15);
    int k0  = ks * 32 + (lane >> 4) * 8;
    const float* W = m ? whh : wih;
    half8 o;
#pragma unroll
    for (int j = 0; j < 8; ++j) o[j] = (_Float16)W[(k0 + j) * 384 + col];
    *(half8*)(wgru + (size_t)u2 * 8) = o;
  }
}

// ---- pull: one wave per node; 2-edge unrolled; writes fp16 agg -------------
__global__ __launch_bounds__(256) void pull_kernel(
    const float* __restrict__ x, const _Float16* __restrict__ xp,
    _Float16* __restrict__ aggh,
    const int* __restrict__ src_csr, const int* __restrict__ off,
    const int* __restrict__ eids, const float* __restrict__ attr,
    const float* __restrict__ eW_l, const float* __restrict__ eb_l,
    int N)
{
  int node = __builtin_amdgcn_readfirstlane(
      blockIdx.x * 4 + (threadIdx.x >> 6));
  if (node >= N) return;
  int c = threadIdx.x & 63;    // lane owns channels {2c, 2c+1}

  float2 w[16];
#pragma unroll
  for (int d = 0; d < 16; ++d) w[d] = ((const float2*)eW_l)[d * 64 + c];
  float2 bq = ((const float2*)eb_l)[c];

  int start = (node == 0) ? 0 : off[node - 1];
  int end   = off[node];

  float2 acc[TC][Bdim];
#pragma unroll
  for (int t = 0; t < TC; ++t)
#pragma unroll
    for (int b = 0; b < Bdim; ++b) { acc[t][b].x = 0.f; acc[t][b].y = 0.f; }

  int i = start;
  for (; i + 2 <= end; i += 2) {          // two independent edges in flight
    int sA = src_csr[i], sB = src_csr[i + 1];
    int eA = eids[i],    eB = eids[i + 1];
    const float* avA = attr + (size_t)eA * 16;
    const float* avB = attr + (size_t)eB * 16;
    float2 emA = bq, emB = bq;
#pragma unroll
    for (int d = 0; d < 16; ++d) {
      float aA = avA[d], aB = avB[d];      // s_loads (uniform)
      emA.x += aA * w[d].x; emA.y += aA * w[d].y;
      emB.x += aB * w[d].x; emB.y += aB * w[d].y;
    }
    const h4* xsA = (const h4*)(xp + (size_t)sA * (TC * Bdim * Hdim));
    const h4* xsB = (const h4*)(xp + (size_t)sB * (TC * Bdim * Hdim));
#pragma unroll
    for (int t = 0; t < TC; ++t) {
      h4 vA = xsA[t * 64 + c];
      h4 vB = xsB[t * 64 + c];
      acc[t][0].x += fmaxf((float)vA.x + emA.x, 0.f);
      acc[t][1].x += fmaxf((float)vA.y + emA.x, 0.f);
      acc[t][0].y += fmaxf((float)vA.z + emA.y, 0.f);
      acc[t][1].y += fmaxf((float)vA.w + emA.y, 0.f);
      acc[t][0].x += fmaxf((float)vB.x + emB.x, 0.f);
      acc[t][1].x += fmaxf((float)vB.y + emB.x, 0.f);
      acc[t][0].y += fmaxf((float)vB.z + emB.y, 0.f);
      acc[t][1].y += fmaxf((float)vB.w + emB.y, 0.f);
    }
  }
  if (i < end) {                           // odd tail edge
    int sA = src_csr[i], eA = eids[i];
    const float* avA = attr + (size_t)eA * 16;
    float2 emA = bq;
#pragma unroll
    for (int d = 0; d < 16; ++d) {
      float aA = avA[d];
      emA.x += aA * w[d].x; emA.y += aA * w[d].y;
    }
    const h4* xsA = (const h4*)(xp + (size_t)sA * (TC * Bdim * Hdim));
#pragma unroll
    for (int t = 0; t < TC; ++t) {
      h4 vA = xsA[t * 64 + c];
      acc[t][0].x += fmaxf((float)vA.x + emA.x, 0.f);
      acc[t][1].x += fmaxf((float)vA.y + emA.x, 0.f);
      acc[t][0].y += fmaxf((float)vA.z + emA.y, 0.f);
      acc[t][1].y += fmaxf((float)vA.w + emA.y, 0.f);
    }
  }

  const float2* x2 = (const float2*)x;
  const float2* xn = x2 + (size_t)node * (TC * Bdim * 64);
  _Float16* an = aggh + (size_t)node * (TC * Bdim * Hdim);
#pragma unroll
  for (int t = 0; t < TC; ++t)
#pragma unroll
    for (int b = 0; b < Bdim; ++b) {
      int tb = t * Bdim + b;
      float2 s = xn[tb * 64 + c];          // self term, exact fp32
      h2 o = { (_Float16)(acc[t][b].x + s.x), (_Float16)(acc[t][b].y + s.y) };
      *(h2*)(an + tb * Hdim + 2 * c) = o;
    }
}

// ------- MLP via MFMA + optional fused gi (x@wih+bias) for the last layer ---
// ONE WAVE PER BLOCK (no barriers anywhere). mid fp16 (bit-identical).
// gi written with DIRECT stores (r15+r17: LDS staging loses).
// DO_GI variant SKIPS the x/xp stores: after the l=1 MLP nothing reads them
// (gru4 uses gi, head uses hgb, next chunk's enc rewrites x/xp) -> 61MB of
// dead stores per dispatch eliminated.
template<int DO_GI>
__global__ __launch_bounds__(64) void mlp_mfma_kernel(
    float* __restrict__ x, _Float16* __restrict__ xp,
    const _Float16* __restrict__ aggh,
    const _Float16* __restrict__ w1p, const _Float16* __restrict__ w2p,
    const float* __restrict__ m1b, const float* __restrict__ m2b,
    const float* __restrict__ lng, const float* __restrict__ lnb,
    const _Float16* __restrict__ wip, const float* __restrict__ bih,
    const float* __restrict__ bhh, _Float16* __restrict__ gi)
{
  __shared__ _Float16 midw[16][136];
  int lane = threadIdx.x;
  int row0 = blockIdx.x * 16;
  int mrow = lane & 15;
  int kgrp = lane >> 4;

  // A frags straight from fp16 agg (contiguous 16B loads)
  half8 afrag[4];
  const _Float16* abase = aggh + (size_t)(row0 + mrow) * Hdim + kgrp * 8;
#pragma unroll
  for (int ks = 0; ks < 4; ++ks)
    afrag[ks] = *(const half8*)(abase + ks * 32);

#pragma unroll
  for (int nt = 0; nt < 8; ++nt) {
    floatx4 acc = {0.f, 0.f, 0.f, 0.f};
#pragma unroll
    for (int ks = 0; ks < 4; ++ks) {
      half8 b = *(const half8*)(w1p + ((size_t)(nt * 4 + ks) * 64 + lane) * 8);
      acc = __builtin_amdgcn_mfma_f32_16x16x32_f16(afrag[ks], b, acc, 0, 0, 0);
    }
    int col = nt * 16 + mrow;
    float bv = m1b[col];
#pragma unroll
    for (int r = 0; r < 4; ++r)
      midw[kgrp * 4 + r][col] = (_Float16)fmaxf(acc[r] + bv, 0.f);
  }
  // single wave: compiler's lgkmcnt ordering covers write->read

  half8 afrag2[4];
#pragma unroll
  for (int ks = 0; ks < 4; ++ks)
    afrag2[ks] = *(const half8*)(&midw[mrow][kgrp * 8 + ks * 32]);

  floatx4 acc2[8];
#pragma unroll
  for (int nt = 0; nt < 8; ++nt) {
    floatx4 acc = {0.f, 0.f, 0.f, 0.f};
#pragma unroll
    for (int ks = 0; ks < 4; ++ks) {
      half8 b = *(const half8*)(w2p + ((size_t)(nt * 4 + ks) * 64 + lane) * 8);
      acc = __builtin_amdgcn_mfma_f32_16x16x32_f16(afrag2[ks], b, acc, 0, 0, 0);
    }
    float bv = m2b[nt * 16 + mrow];
#pragma unroll
    for (int r = 0; r < 4; ++r) acc[r] += bv;
    acc2[nt] = acc;
  }

  float s1[4] = {0.f, 0.f, 0.f, 0.f}, s2[4] = {0.f, 0.f, 0.f, 0.f};
#pragma unroll
  for (int nt = 0; nt < 8; ++nt)
#pragma unroll
    for (int r = 0; r < 4; ++r) {
      float v = acc2[nt][r];
      s1[r] += v; s2[r] += v * v;
    }
#pragma unroll
  for (int r = 0; r < 4; ++r) {
#pragma unroll
    for (int o = 1; o < 16; o <<= 1) {
      s1[r] += __shfl_xor(s1[r], o);
      s2[r] += __shfl_xor(s2[r], o);
    }
  }
  float mu[4], rstd[4];
#pragma unroll
  for (int r = 0; r < 4; ++r) {
    mu[r] = s1[r] * (1.f / Hdim);
    float var = fmaxf(s2[r] * (1.f / Hdim) - mu[r] * mu[r], 0.f);
    rstd[r] = rsqrtf(var + 1e-5f);
  }

#pragma unroll
  for (int nt = 0; nt < 8; ++nt) {
    int col = nt * 16 + mrow;
    float g = lng[col], bb = lnb[col];
#pragma unroll
    for (int r = 0; r < 4; ++r) {
      int row = row0 + kgrp * 4 + r;
      float y = (acc2[nt][r] - mu[r]) * rstd[r] * g + bb;
      float xr = x[(size_t)row * Hdim + col];
      float o = fmaxf(y, 0.f) + xr;
      if (!DO_GI) {
        x[(size_t)row * Hdim + col] = o;
        xp[((size_t)(row >> 1) * Hdim + col) * 2 + (row & 1)] = (_Float16)o;
      } else {
        midw[kgrp * 4 + r][col] = (_Float16)o;  // stage new x for gi only
      }
    }
  }

  if (DO_GI) {
    // gi A-frags from the staged fp16 new-x (same rounding as before)
    half8 ax[4];
#pragma unroll
    for (int ks = 0; ks < 4; ++ks)
      ax[ks] = *(const half8*)(&midw[mrow][kgrp * 8 + ks * 32]);
#pragma unroll
    for (int nt = 0; nt < 24; ++nt) {
      int col = nt * 16 + mrow;
      float bv = bih[col] + ((nt < 16) ? bhh[col] : 0.f);
      floatx4 a = {bv, bv, bv, bv};
#pragma unroll
      for (int ks = 0; ks < 4; ++ks) {
        half8 bf = *(const half8*)(wip + ((size_t)(nt * 4 + ks) * 64 + lane) * 8);
        a = __builtin_amdgcn_mfma_f32_16x16x32_f16(ax[ks], bf, a, 0, 0, 0);
      }
#pragma unroll
      for (int r = 0; r < 4; ++r)
        gi[(size_t)(row0 + kgrp * 4 + r) * 384 + col] = (_Float16)a[r];
    }
  }
}

// ---- fused 4-step GRU v3: column-split across 4 waves ----------------------
__global__ __launch_bounds__(256) void gru4_kernel(
    float* __restrict__ hg, const _Float16* __restrict__ whp,
    const float* __restrict__ bhh, const _Float16* __restrict__ gi, int N)
{
  __shared__ _Float16 hl[16][136];
  int wv = threadIdx.x >> 6, lane = threadIdx.x & 63;
  int row0 = blockIdx.x * 16;
  int mcol = lane & 15, kgrp = lane >> 4;
  int sr0 = row0 + kgrp * 4;

  float hreg[2][4];
#pragma unroll
  for (int j = 0; j < 2; ++j) {
    int col = (wv * 2 + j) * 16 + mcol;
#pragma unroll
    for (int r = 0; r < 4; ++r) {
      float v = hg[(size_t)(sr0 + r) * Hdim + col];
      hreg[j][r] = v;
      hl[kgrp * 4 + r][col] = (_Float16)v;
    }
  }
  __syncthreads();

  float bn[2];
#pragma unroll
  for (int j = 0; j < 2; ++j) bn[j] = bhh[256 + (wv * 2 + j) * 16 + mcol];

  for (int tin = 0; tin < TC; ++tin) {
    half8 ah[4];
#pragma unroll
    for (int ks = 0; ks < 4; ++ks)
      ah[ks] = *(const half8*)(&hl[mcol][ks * 32 + kgrp * 8]);

    int cr[4];
#pragma unroll
    for (int r = 0; r < 4; ++r) {
      int sr = sr0 + r;
      int b = sr >= N;
      int n = sr - b * N;
      cr[r] = (n * TC + tin) * Bdim + b;
    }

    floatx4 ar[2], az[2], ahn[2];
    float gn[2][4];
#pragma unroll
    for (int j = 0; j < 2; ++j) {
      int col = (wv * 2 + j) * 16 + mcol;
#pragma unroll
      for (int r = 0; r < 4; ++r) {
        ar[j][r] = (float)gi[(size_t)cr[r] * 384 + col];
        az[j][r] = (float)gi[(size_t)cr[r] * 384 + 128 + col];
        gn[j][r] = (float)gi[(size_t)cr[r] * 384 + 256 + col];
      }
    }
#pragma unroll
    for (int j = 0; j < 2; ++j) {
      int nt = wv * 2 + j;
      floatx4 an4 = {bn[j], bn[j], bn[j], bn[j]};
#pragma unroll
      for (int ks = 0; ks < 4; ++ks) {
        half8 bfr = *(const half8*)(whp + ((size_t)(nt * 4 + ks) * 64 + lane) * 8);
        ar[j] = __builtin_amdgcn_mfma_f32_16x16x32_f16(ah[ks], bfr, ar[j], 0, 0, 0);
        half8 bfz = *(const half8*)(whp + ((size_t)((8 + nt) * 4 + ks) * 64 + lane) * 8);
        az[j] = __builtin_amdgcn_mfma_f32_16x16x32_f16(ah[ks], bfz, az[j], 0, 0, 0);
        half8 bfn = *(const half8*)(whp + ((size_t)((16 + nt) * 4 + ks) * 64 + lane) * 8);
        an4 = __builtin_amdgcn_mfma_f32_16x16x32_f16(ah[ks], bfn, an4, 0, 0, 0);
      }
      ahn[j] = an4;
    }

    __syncthreads();   // all waves' ds_reads of hl complete before overwrite
#pragma unroll
    for (int j = 0; j < 2; ++j) {
      int col = (wv * 2 + j) * 16 + mcol;
#pragma unroll
      for (int r = 0; r < 4; ++r) {
        float rg = sigm(ar[j][r]);
        float zg = sigm(az[j][r]);
        float u = gn[j][r] + rg * ahn[j][r];
        float ng = 2.f / (1.f + __expf(-2.f * u)) - 1.f;   // tanh
        float hnew = (1.f - zg) * ng + zg * hreg[j][r];
        hreg[j][r] = hnew;
        hl[kgrp * 4 + r][col] = (_Float16)hnew;
      }
    }
    __syncthreads();
  }

#pragma unroll
  for (int j = 0; j < 2; ++j) {
    int col = (wv * 2 + j) * 16 + mcol;
#pragma unroll
    for (int r = 0; r < 4; ++r)
      hg[(size_t)(sr0 + r) * Hdim + col] = hreg[j][r];
  }
}

// ---------------- head: out[row] = dot(h[row], head_w) + head_b -------------
__global__ __launch_bounds__(128) void head_kernel(
    const float* __restrict__ hg, const float* __restrict__ hw,
    const float* __restrict__ hb, float* __restrict__ out)
{
  int row = blockIdx.x;
  int j = threadIdx.x;
  __shared__ float red[2];
  float v = hg[(size_t)row * Hdim + j] * hw[j];
#pragma unroll
  for (int off = 32; off >= 1; off >>= 1) v += __shfl_xor(v, off);
  int wid = j >> 6, lane = j & 63;
  if (lane == 0) red[wid] = v;
  __syncthreads();
  if (j == 0) out[row] = red[0] + red[1] + hb[0];
}

extern "C" void kernel_launch(void* const* d_in, const int* in_sizes, int n_in,
                              void* d_out, int out_size, void* d_ws, size_t ws_size,
                              hipStream_t stream)
{
  const float* xseq  = (const float*)d_in[0];
  const int*   ei    = (const int*)d_in[1];
  const float* attr  = (const float*)d_in[2];
  const float* enc_w = (const float*)d_in[3];
  const float* enc_b = (const float*)d_in[4];
  const float* eW    = (const float*)d_in[5];
  const float* eb    = (const float*)d_in[6];
  const float* m1w   = (const float*)d_in[7];
  const float* m1b   = (const float*)d_in[8];
  const float* m2w   = (const float*)d_in[9];
  const float* m2b   = (const float*)d_in[10];
  const float* lng   = (const float*)d_in[11];
  const float* lnb   = (const float*)d_in[12];
  const float* wih   = (const float*)d_in[13];
  const float* whh   = (const float*)d_in[14];
  const float* bih   = (const float*)d_in[15];
  const float* bhh   = (const float*)d_in[16];
  const float* hw    = (const float*)d_in[17];
  const float* hb    = (const float*)d_in[18];

  int E = in_sizes[1] / 2;
  int N = in_sizes[0] / (Bdim * Tdim * Fdim);
  int rowsState = Bdim * N;                    // 20000
  int rowsC = TC * Bdim * N;                   // 80000
  size_t SC = (size_t)rowsC * Hdim;
  size_t SS = (size_t)rowsState * Hdim;

  float*     x    = (float*)d_ws;              // SC floats
  float*     hgb  = x + SC;                    // SS floats
  _Float16*  aggh = (_Float16*)(hgb + SS);     // fp16 agg, SC halfs
  _Float16*  xp   = aggh + SC;                 // paired fp16 shadow, SC halfs
  _Float16*  wpk  = xp + SC;                   // MLP packed: 4 * 16384 halfs
  _Float16*  wgru = wpk + 4 * 16384;           // GRU packed: 12288*8 halfs
  _Float16*  gi   = wgru + 98304;              // [rowsC][384] fp16
  int*   cnt  = (int*)(gi + (size_t)rowsC * 384);
  int*   off  = cnt + N;
  int*   eids = off + (N + 1);
  int*   src_csr = eids + E;

  hipMemsetAsync(hgb, 0, SS * sizeof(float), stream);
  hipMemsetAsync(cnt, 0, N * sizeof(int), stream);

  int eBlocks    = (E + 255) / 256;
  int encBlocks  = (N * TC * 32 + 255) / 256;  // 5000
  int mlpBlocks  = rowsC / 16;                 // 5000 (64-thread blocks)
  int gruBlocks  = rowsState / 16;             // 1250
  int pullBlocks = (N + 3) / 4;                // 2500

  count_kernel<<<eBlocks, 256, 0, stream>>>(ei, cnt, E);
  scan_kernel<<<1, 1024, 0, stream>>>(cnt, off, N);
  fill_kernel<<<eBlocks, 256, 0, stream>>>(ei, off, eids, src_csr, E);
  pack_all_kernel<<<80, 256, 0, stream>>>(m1w, m2w, wih, whh, wpk, wgru);

  for (int c = 0; c < Tdim / TC; ++c) {
    enc_kernel<<<encBlocks, 256, 0, stream>>>(xseq, enc_w, enc_b, x, xp, N, c * TC);
    for (int l = 0; l < 2; ++l) {
      pull_kernel<<<pullBlocks, 256, 0, stream>>>(
          x, xp, aggh, src_csr, off, eids, attr,
          eW + (size_t)l * Ddim * Hdim, eb + (size_t)l * Hdim, N);
      if (l == 0) {
        mlp_mfma_kernel<0><<<mlpBlocks, 64, 0, stream>>>(
            x, xp, aggh,
            wpk + (size_t)0 * 16384, wpk + (size_t)1 * 16384,
            m1b, m2b, lng, lnb, nullptr, nullptr, nullptr, nullptr);
      } else {
        mlp_mfma_kernel<1><<<mlpBlocks, 64, 0, stream>>>(
            x, xp, aggh,
            wpk + (size_t)2 * 16384, wpk + (size_t)3 * 16384,
            m1b + Hdim, m2b + Hdim, lng + Hdim, lnb + Hdim,
            wgru, bih, bhh, gi);
      }
    }
    gru4_kernel<<<gruBlocks, 256, 0, stream>>>(hgb, wgru + 6144 * 8, bhh, gi, N);
  }
  head_kernel<<<rowsState, 128, 0, stream>>>(hgb, hw, hb, (float*)d_out);
}

// Round 21
// 663.999 us; speedup vs baseline: 1.2826x; 1.0755x over previous
//
#include <hip/hip_runtime.h>

#define Hdim 128
#define Fdim 16
#define Ddim 16
#define Tdim 8
#define Bdim 2
#define TC 4          // timesteps per chunk (2 chunks)

typedef _Float16 h2 __attribute__((ext_vector_type(2)));
typedef _Float16 h4 __attribute__((ext_vector_type(4)));
typedef _Float16 half8 __attribute__((ext_vector_type(8)));
typedef float floatx4 __attribute__((ext_vector_type(4)));

__device__ __forceinline__ float sigm(float u) { return 1.f / (1.f + __expf(-u)); }

// All node features live ONLY in the fp16 batch-paired shadow xp:
//   elem ((n*TC+tin)*128 + ch)*2 + b.  (fp32 x eliminated in r21: its only
// consumers -- pull self-term, mlp residual -- read fp16(x) anyway-adjacent
// values; saves ~250MB traffic/run.)
// aggh (fp16) and gi (fp16) are row-major [row][*], row=(n*TC+tin)*Bdim+b.

// ---------------- encoder: one thread computes BOTH batches -----------------
__global__ __launch_bounds__(256) void enc_kernel(
    const float* __restrict__ xseq, const float* __restrict__ enc_w,
    const float* __restrict__ enc_b, _Float16* __restrict__ xp, int N, int t0)
{
  int gid = blockIdx.x * 256 + threadIdx.x;
  int ntr = gid >> 5;          // n*TC + tin
  int q   = gid & 31;          // channel quad
  if (ntr >= N * TC) return;
  int tin = ntr & (TC - 1);
  int n   = ntr >> 2;          // TC == 4
  const float* xs0 = xseq + (((size_t)(t0 + tin)) * N + n) * Fdim;
  const float* xs1 = xs0 + (size_t)Tdim * N * Fdim;
  float4 bq = ((const float4*)enc_b)[q];
  float4 a0 = bq, a1 = bq;
#pragma unroll
  for (int f = 0; f < Fdim; ++f) {
    float s0 = xs0[f], s1 = xs1[f];
    float4 w = ((const float4*)enc_w)[f * (Hdim / 4) + q];
    a0.x += s0 * w.x; a0.y += s0 * w.y; a0.z += s0 * w.z; a0.w += s0 * w.w;
    a1.x += s1 * w.x; a1.y += s1 * w.y; a1.z += s1 * w.z; a1.w += s1 * w.w;
  }
  half8 hv = { (_Float16)a0.x, (_Float16)a1.x, (_Float16)a0.y, (_Float16)a1.y,
               (_Float16)a0.z, (_Float16)a1.z, (_Float16)a0.w, (_Float16)a1.w };
  *(half8*)(xp + ((size_t)ntr * Hdim + q * 4) * 2) = hv;
}

// ---------------- CSR build: count, scan, fill ------------------------------
__global__ __launch_bounds__(256) void count_kernel(
    const int* __restrict__ ei, int* __restrict__ cnt, int E)
{
  int e = blockIdx.x * 256 + threadIdx.x;
  if (e < E) atomicAdd(&cnt[ei[E + e]], 1);
}

__global__ __launch_bounds__(1024) void scan_kernel(
    const int* __restrict__ cnt, int* __restrict__ off, int N)
{
  __shared__ int part[1024];
  int tid = threadIdx.x;
  int per = (N + 1023) / 1024;
  int base = tid * per;
  int s = 0;
  for (int i = 0; i < per; ++i) { int idx = base + i; if (idx < N) s += cnt[idx]; }
  part[tid] = s;
  __syncthreads();
  for (int d = 1; d < 1024; d <<= 1) {
    int v = (tid >= d) ? part[tid - d] : 0;
    __syncthreads();
    part[tid] += v;
    __syncthreads();
  }
  int run = (tid == 0) ? 0 : part[tid - 1];
  for (int i = 0; i < per; ++i) {
    int idx = base + i;
    if (idx < N) { off[idx] = run; run += cnt[idx]; }
  }
  if (tid == 1023) off[N] = part[1023];
}

__global__ __launch_bounds__(256) void fill_kernel(
    const int* __restrict__ ei, int* __restrict__ off,
    int* __restrict__ eids, int* __restrict__ src_csr, int E)
{
  int e = blockIdx.x * 256 + threadIdx.x;
  if (e < E) {
    int d = ei[E + e];
    int pos = atomicAdd(&off[d], 1);
    eids[pos] = e;
    src_csr[pos] = ei[e];
  }
}

// ---- pack ALL weights (MLP m1w/m2w x2 layers + GRU wih|whh) in one kernel --
__global__ __launch_bounds__(256) void pack_all_kernel(
    const float* __restrict__ m1w, const float* __restrict__ m2w,
    const float* __restrict__ wih, const float* __restrict__ whh,
    _Float16* __restrict__ wpk, _Float16* __restrict__ wgru)
{
  int t = blockIdx.x * 256 + threadIdx.x;
  if (t < 8192) {                 // MLP: which = 2*l + is_m2
    int u = t & 2047, which = t >> 11;
    const float* W = ((which & 1) ? m2w : m1w) + (size_t)(which >> 1) * Hdim * Hdim;
    _Float16* Wp = wpk + (size_t)which * 16384;
    int lane = u & 63, ks = (u >> 6) & 3, nt = u >> 8;
    int col = nt * 16 + (lane & 15);
    int k0  = ks * 32 + (lane >> 4) * 8;
    half8 o;
#pragma unroll
    for (int j = 0; j < 8; ++j) o[j] = (_Float16)W[(k0 + j) * Hdim + col];
    *(half8*)(Wp + (size_t)u * 8) = o;
  } else if (t < 8192 + 12288) {  // GRU
    int u2 = t - 8192;
    int m = u2 >= 6144;
    int u = m ? u2 - 6144 : u2;
    int lane = u & 63, ks = (u >> 6) & 3, nt = u >> 8;
    int col = nt * 16 + (lane & 15);
    int k0  = ks * 32 + (lane >> 4) * 8;
    const float* W = m ? whh : wih;
    half8 o;
#pragma unroll
    for (int j = 0; j < 8; ++j) o[j] = (_Float16)W[(k0 + j) * 384 + col];
    *(half8*)(wgru + (size_t)u2 * 8) = o;
  }
}

// ---- pull: one wave per node; 2-edge unrolled; self term from xp -----------
__global__ __launch_bounds__(256) void pull_kernel(
    const _Float16* __restrict__ xp, _Float16* __restrict__ aggh,
    const int* __restrict__ src_csr, const int* __restrict__ off,
    const int* __restrict__ eids, const float* __restrict__ attr,
    const float* __restrict__ eW_l, const float* __restrict__ eb_l,
    int N)
{
  int node = __builtin_amdgcn_readfirstlane(
      blockIdx.x * 4 + (threadIdx.x >> 6));
  if (node >= N) return;
  int c = threadIdx.x & 63;    // lane owns channels {2c, 2c+1}

  float2 w[16];
#pragma unroll
  for (int d = 0; d < 16; ++d) w[d] = ((const float2*)eW_l)[d * 64 + c];
  float2 bq = ((const float2*)eb_l)[c];

  int start = (node == 0) ? 0 : off[node - 1];
  int end   = off[node];

  float2 acc[TC][Bdim];
#pragma unroll
  for (int t = 0; t < TC; ++t)
#pragma unroll
    for (int b = 0; b < Bdim; ++b) { acc[t][b].x = 0.f; acc[t][b].y = 0.f; }

  int i = start;
  for (; i + 2 <= end; i += 2) {          // two independent edges in flight
    int sA = src_csr[i], sB = src_csr[i + 1];
    int eA = eids[i],    eB = eids[i + 1];
    const float* avA = attr + (size_t)eA * 16;
    const float* avB = attr + (size_t)eB * 16;
    float2 emA = bq, emB = bq;
#pragma unroll
    for (int d = 0; d < 16; ++d) {
      float aA = avA[d], aB = avB[d];      // s_loads (uniform)
      emA.x += aA * w[d].x; emA.y += aA * w[d].y;
      emB.x += aB * w[d].x; emB.y += aB * w[d].y;
    }
    const h4* xsA = (const h4*)(xp + (size_t)sA * (TC * Bdim * Hdim));
    const h4* xsB = (const h4*)(xp + (size_t)sB * (TC * Bdim * Hdim));
#pragma unroll
    for (int t = 0; t < TC; ++t) {
      h4 vA = xsA[t * 64 + c];
      h4 vB = xsB[t * 64 + c];
      acc[t][0].x += fmaxf((float)vA.x + emA.x, 0.f);
      acc[t][1].x += fmaxf((float)vA.y + emA.x, 0.f);
      acc[t][0].y += fmaxf((float)vA.z + emA.y, 0.f);
      acc[t][1].y += fmaxf((float)vA.w + emA.y, 0.f);
      acc[t][0].x += fmaxf((float)vB.x + emB.x, 0.f);
      acc[t][1].x += fmaxf((float)vB.y + emB.x, 0.f);
      acc[t][0].y += fmaxf((float)vB.z + emB.y, 0.f);
      acc[t][1].y += fmaxf((float)vB.w + emB.y, 0.f);
    }
  }
  if (i < end) {                           // odd tail edge
    int sA = src_csr[i], eA = eids[i];
    const float* avA = attr + (size_t)eA * 16;
    float2 emA = bq;
#pragma unroll
    for (int d = 0; d < 16; ++d) {
      float aA = avA[d];
      emA.x += aA * w[d].x; emA.y += aA * w[d].y;
    }
    const h4* xsA = (const h4*)(xp + (size_t)sA * (TC * Bdim * Hdim));
#pragma unroll
    for (int t = 0; t < TC; ++t) {
      h4 vA = xsA[t * 64 + c];
      acc[t][0].x += fmaxf((float)vA.x + emA.x, 0.f);
      acc[t][1].x += fmaxf((float)vA.y + emA.x, 0.f);
      acc[t][0].y += fmaxf((float)vA.z + emA.y, 0.f);
      acc[t][1].y += fmaxf((float)vA.w + emA.y, 0.f);
    }
  }

  const h4* xn = (const h4*)(xp + (size_t)node * (TC * Bdim * Hdim));
  _Float16* an = aggh + (size_t)node * (TC * Bdim * Hdim);
#pragma unroll
  for (int t = 0; t < TC; ++t) {
    h4 sv = xn[t * 64 + c];                // self term (fp16 shadow)
    h2 o0 = { (_Float16)(acc[t][0].x + (float)sv.x),
              (_Float16)(acc[t][0].y + (float)sv.z) };
    h2 o1 = { (_Float16)(acc[t][1].x + (float)sv.y),
              (_Float16)(acc[t][1].y + (float)sv.w) };
    *(h2*)(an + (t * Bdim + 0) * Hdim + 2 * c) = o0;
    *(h2*)(an + (t * Bdim + 1) * Hdim + 2 * c) = o1;
  }
}

// ------- MLP via MFMA + optional fused gi (x@wih+bias) for the last layer ---
// ONE WAVE PER BLOCK (no barriers). mid fp16. Residual read from xp (fp16).
// DO_GI=0 writes the new x only to xp; DO_GI=1 writes only gi (x/xp dead).
template<int DO_GI>
__global__ __launch_bounds__(64) void mlp_mfma_kernel(
    _Float16* __restrict__ xp, const _Float16* __restrict__ aggh,
    const _Float16* __restrict__ w1p, const _Float16* __restrict__ w2p,
    const float* __restrict__ m1b, const float* __restrict__ m2b,
    const float* __restrict__ lng, const float* __restrict__ lnb,
    const _Float16* __restrict__ wip, const float* __restrict__ bih,
    const float* __restrict__ bhh, _Float16* __restrict__ gi)
{
  __shared__ _Float16 midw[16][136];
  int lane = threadIdx.x;
  int row0 = blockIdx.x * 16;
  int mrow = lane & 15;
  int kgrp = lane >> 4;

  // A frags straight from fp16 agg (contiguous 16B loads)
  half8 afrag[4];
  const _Float16* abase = aggh + (size_t)(row0 + mrow) * Hdim + kgrp * 8;
#pragma unroll
  for (int ks = 0; ks < 4; ++ks)
    afrag[ks] = *(const half8*)(abase + ks * 32);

#pragma unroll
  for (int nt = 0; nt < 8; ++nt) {
    floatx4 acc = {0.f, 0.f, 0.f, 0.f};
#pragma unroll
    for (int ks = 0; ks < 4; ++ks) {
      half8 b = *(const half8*)(w1p + ((size_t)(nt * 4 + ks) * 64 + lane) * 8);
      acc = __builtin_amdgcn_mfma_f32_16x16x32_f16(afrag[ks], b, acc, 0, 0, 0);
    }
    int col = nt * 16 + mrow;
    float bv = m1b[col];
#pragma unroll
    for (int r = 0; r < 4; ++r)
      midw[kgrp * 4 + r][col] = (_Float16)fmaxf(acc[r] + bv, 0.f);
  }
  // single wave: compiler's lgkmcnt ordering covers write->read

  half8 afrag2[4];
#pragma unroll
  for (int ks = 0; ks < 4; ++ks)
    afrag2[ks] = *(const half8*)(&midw[mrow][kgrp * 8 + ks * 32]);

  floatx4 acc2[8];
#pragma unroll
  for (int nt = 0; nt < 8; ++nt) {
    floatx4 acc = {0.f, 0.f, 0.f, 0.f};
#pragma unroll
    for (int ks = 0; ks < 4; ++ks) {
      half8 b = *(const half8*)(w2p + ((size_t)(nt * 4 + ks) * 64 + lane) * 8);
      acc = __builtin_amdgcn_mfma_f32_16x16x32_f16(afrag2[ks], b, acc, 0, 0, 0);
    }
    float bv = m2b[nt * 16 + mrow];
#pragma unroll
    for (int r = 0; r < 4; ++r) acc[r] += bv;
    acc2[nt] = acc;
  }

  float s1[4] = {0.f, 0.f, 0.f, 0.f}, s2[4] = {0.f, 0.f, 0.f, 0.f};
#pragma unroll
  for (int nt = 0; nt < 8; ++nt)
#pragma unroll
    for (int r = 0; r < 4; ++r) {
      float v = acc2[nt][r];
      s1[r] += v; s2[r] += v * v;
    }
#pragma unroll
  for (int r = 0; r < 4; ++r) {
#pragma unroll
    for (int o = 1; o < 16; o <<= 1) {
      s1[r] += __shfl_xor(s1[r], o);
      s2[r] += __shfl_xor(s2[r], o);
    }
  }
  float mu[4], rstd[4];
#pragma unroll
  for (int r = 0; r < 4; ++r) {
    mu[r] = s1[r] * (1.f / Hdim);
    float var = fmaxf(s2[r] * (1.f / Hdim) - mu[r] * mu[r], 0.f);
    rstd[r] = rsqrtf(var + 1e-5f);
  }

#pragma unroll
  for (int nt = 0; nt < 8; ++nt) {
    int col = nt * 16 + mrow;
    float g = lng[col], bb = lnb[col];
#pragma unroll
    for (int r = 0; r < 4; ++r) {
      int row = row0 + kgrp * 4 + r;
      float y = (acc2[nt][r] - mu[r]) * rstd[r] * g + bb;
      float xr = (float)xp[((size_t)(row >> 1) * Hdim + col) * 2 + (row & 1)];
      float o = fmaxf(y, 0.f) + xr;
      if (!DO_GI) {
        xp[((size_t)(row >> 1) * Hdim + col) * 2 + (row & 1)] = (_Float16)o;
      } else {
        midw[kgrp * 4 + r][col] = (_Float16)o;  // stage new x for gi only
      }
    }
  }

  if (DO_GI) {
    // gi A-frags from the staged fp16 new-x
    half8 ax[4];
#pragma unroll
    for (int ks = 0; ks < 4; ++ks)
      ax[ks] = *(const half8*)(&midw[mrow][kgrp * 8 + ks * 32]);
#pragma unroll
    for (int nt = 0; nt < 24; ++nt) {
      int col = nt * 16 + mrow;
      float bv = bih[col] + ((nt < 16) ? bhh[col] : 0.f);
      floatx4 a = {bv, bv, bv, bv};
#pragma unroll
      for (int ks = 0; ks < 4; ++ks) {
        half8 bf = *(const half8*)(wip + ((size_t)(nt * 4 + ks) * 64 + lane) * 8);
        a = __builtin_amdgcn_mfma_f32_16x16x32_f16(ax[ks], bf, a, 0, 0, 0);
      }
#pragma unroll
      for (int r = 0; r < 4; ++r)
        gi[(size_t)(row0 + kgrp * 4 + r) * 384 + col] = (_Float16)a[r];
    }
  }
}

// ---- fused 4-step GRU v3: column-split across 4 waves ----------------------
__global__ __launch_bounds__(256) void gru4_kernel(
    float* __restrict__ hg, const _Float16* __restrict__ whp,
    const float* __restrict__ bhh, const _Float16* __restrict__ gi, int N)
{
  __shared__ _Float16 hl[16][136];
  int wv = threadIdx.x >> 6, lane = threadIdx.x & 63;
  int row0 = blockIdx.x * 16;
  int mcol = lane & 15, kgrp = lane >> 4;
  int sr0 = row0 + kgrp * 4;

  float hreg[2][4];
#pragma unroll
  for (int j = 0; j < 2; ++j) {
    int col = (wv * 2 + j) * 16 + mcol;
#pragma unroll
    for (int r = 0; r < 4; ++r) {
      float v = hg[(size_t)(sr0 + r) * Hdim + col];
      hreg[j][r] = v;
      hl[kgrp * 4 + r][col] = (_Float16)v;
    }
  }
  __syncthreads();

  float bn[2];
#pragma unroll
  for (int j = 0; j < 2; ++j) bn[j] = bhh[256 + (wv * 2 + j) * 16 + mcol];

  for (int tin = 0; tin < TC; ++tin) {
    half8 ah[4];
#pragma unroll
    for (int ks = 0; ks < 4; ++ks)
      ah[ks] = *(const half8*)(&hl[mcol][ks * 32 + kgrp * 8]);

    int cr[4];
#pragma unroll
    for (int r = 0; r < 4; ++r) {
      int sr = sr0 + r;
      int b = sr >= N;
      int n = sr - b * N;
      cr[r] = (n * TC + tin) * Bdim + b;
    }

    floatx4 ar[2], az[2], ahn[2];
    float gn[2][4];
#pragma unroll
    for (int j = 0; j < 2; ++j) {
      int col = (wv * 2 + j) * 16 + mcol;
#pragma unroll
      for (int r = 0; r < 4; ++r) {
        ar[j][r] = (float)gi[(size_t)cr[r] * 384 + col];
        az[j][r] = (float)gi[(size_t)cr[r] * 384 + 128 + col];
        gn[j][r] = (float)gi[(size_t)cr[r] * 384 + 256 + col];
      }
    }
#pragma unroll
    for (int j = 0; j < 2; ++j) {
      int nt = wv * 2 + j;
      floatx4 an4 = {bn[j], bn[j], bn[j], bn[j]};
#pragma unroll
      for (int ks = 0; ks < 4; ++ks) {
        half8 bfr = *(const half8*)(whp + ((size_t)(nt * 4 + ks) * 64 + lane) * 8);
        ar[j] = __builtin_amdgcn_mfma_f32_16x16x32_f16(ah[ks], bfr, ar[j], 0, 0, 0);
        half8 bfz = *(const half8*)(whp + ((size_t)((8 + nt) * 4 + ks) * 64 + lane) * 8);
        az[j] = __builtin_amdgcn_mfma_f32_16x16x32_f16(ah[ks], bfz, az[j], 0, 0, 0);
        half8 bfn = *(const half8*)(whp + ((size_t)((16 + nt) * 4 + ks) * 64 + lane) * 8);
        an4 = __builtin_amdgcn_mfma_f32_16x16x32_f16(ah[ks], bfn, an4, 0, 0, 0);
      }
      ahn[j] = an4;
    }

    __syncthreads();   // all waves' ds_reads of hl complete before overwrite
#pragma unroll
    for (int j = 0; j < 2; ++j) {
      int col = (wv * 2 + j) * 16 + mcol;
#pragma unroll
      for (int r = 0; r < 4; ++r) {
        float rg = sigm(ar[j][r]);
        float zg = sigm(az[j][r]);
        float u = gn[j][r] + rg * ahn[j][r];
        float ng = 2.f / (1.f + __expf(-2.f * u)) - 1.f;   // tanh
        float hnew = (1.f - zg) * ng + zg * hreg[j][r];
        hreg[j][r] = hnew;
        hl[kgrp * 4 + r][col] = (_Float16)hnew;
      }
    }
    __syncthreads();
  }

#pragma unroll
  for (int j = 0; j < 2; ++j) {
    int col = (wv * 2 + j) * 16 + mcol;
#pragma unroll
    for (int r = 0; r < 4; ++r)
      hg[(size_t)(sr0 + r) * Hdim + col] = hreg[j][r];
  }
}

// ---------------- head: out[row] = dot(h[row], head_w) + head_b -------------
__global__ __launch_bounds__(128) void head_kernel(
    const float* __restrict__ hg, const float* __restrict__ hw,
    const float* __restrict__ hb, float* __restrict__ out)
{
  int row = blockIdx.x;
  int j = threadIdx.x;
  __shared__ float red[2];
  float v = hg[(size_t)row * Hdim + j] * hw[j];
#pragma unroll
  for (int off = 32; off >= 1; off >>= 1) v += __shfl_xor(v, off);
  int wid = j >> 6, lane = j & 63;
  if (lane == 0) red[wid] = v;
  __syncthreads();
  if (j == 0) out[row] = red[0] + red[1] + hb[0];
}

extern "C" void kernel_launch(void* const* d_in, const int* in_sizes, int n_in,
                              void* d_out, int out_size, void* d_ws, size_t ws_size,
                              hipStream_t stream)
{
  const float* xseq  = (const float*)d_in[0];
  const int*   ei    = (const int*)d_in[1];
  const float* attr  = (const float*)d_in[2];
  const float* enc_w = (const float*)d_in[3];
  const float* enc_b = (const float*)d_in[4];
  const float* eW    = (const float*)d_in[5];
  const float* eb    = (const float*)d_in[6];
  const float* m1w   = (const float*)d_in[7];
  const float* m1b   = (const float*)d_in[8];
  const float* m2w   = (const float*)d_in[9];
  const float* m2b   = (const float*)d_in[10];
  const float* lng   = (const float*)d_in[11];
  const float* lnb   = (const float*)d_in[12];
  const float* wih   = (const float*)d_in[13];
  const float* whh   = (const float*)d_in[14];
  const float* bih   = (const float*)d_in[15];
  const float* bhh   = (const float*)d_in[16];
  const float* hw    = (const float*)d_in[17];
  const float* hb    = (const float*)d_in[18];

  int E = in_sizes[1] / 2;
  int N = in_sizes[0] / (Bdim * Tdim * Fdim);
  int rowsState = Bdim * N;                    // 20000
  int rowsC = TC * Bdim * N;                   // 80000
  size_t SC = (size_t)rowsC * Hdim;
  size_t SS = (size_t)rowsState * Hdim;

  float*     hgb  = (float*)d_ws;              // SS floats
  _Float16*  aggh = (_Float16*)(hgb + SS);     // fp16 agg, SC halfs
  _Float16*  xp   = aggh + SC;                 // paired fp16 shadow, SC halfs
  _Float16*  wpk  = xp + SC;                   // MLP packed: 4 * 16384 halfs
  _Float16*  wgru = wpk + 4 * 16384;           // GRU packed: 12288*8 halfs
  _Float16*  gi   = wgru + 98304;              // [rowsC][384] fp16
  int*   cnt  = (int*)(gi + (size_t)rowsC * 384);
  int*   off  = cnt + N;
  int*   eids = off + (N + 1);
  int*   src_csr = eids + E;

  hipMemsetAsync(hgb, 0, SS * sizeof(float), stream);
  hipMemsetAsync(cnt, 0, N * sizeof(int), stream);

  int eBlocks    = (E + 255) / 256;
  int encBlocks  = (N * TC * 32 + 255) / 256;  // 5000
  int mlpBlocks  = rowsC / 16;                 // 5000 (64-thread blocks)
  int gruBlocks  = rowsState / 16;             // 1250
  int pullBlocks = (N + 3) / 4;                // 2500

  count_kernel<<<eBlocks, 256, 0, stream>>>(ei, cnt, E);
  scan_kernel<<<1, 1024, 0, stream>>>(cnt, off, N);
  fill_kernel<<<eBlocks, 256, 0, stream>>>(ei, off, eids, src_csr, E);
  pack_all_kernel<<<80, 256, 0, stream>>>(m1w, m2w, wih, whh, wpk, wgru);

  for (int c = 0; c < Tdim / TC; ++c) {
    enc_kernel<<<encBlocks, 256, 0, stream>>>(xseq, enc_w, enc_b, xp, N, c * TC);
    for (int l = 0; l < 2; ++l) {
      pull_kernel<<<pullBlocks, 256, 0, stream>>>(
          xp, aggh, src_csr, off, eids, attr,
          eW + (size_t)l * Ddim * Hdim, eb + (size_t)l * Hdim, N);
      if (l == 0) {
        mlp_mfma_kernel<0><<<mlpBlocks, 64, 0, stream>>>(
            xp, aggh,
            wpk + (size_t)0 * 16384, wpk + (size_t)1 * 16384,
            m1b, m2b, lng, lnb, nullptr, nullptr, nullptr, nullptr);
      } else {
        mlp_mfma_kernel<1><<<mlpBlocks, 64, 0, stream>>>(
            xp, aggh,
            wpk + (size_t)2 * 16384, wpk + (size_t)3 * 16384,
            m1b + Hdim, m2b + Hdim, lng + Hdim, lnb + Hdim,
            wgru, bih, bhh, gi);
      }
    }
    gru4_kernel<<<gruBlocks, 256, 0, stream>>>(hgb, wgru + 6144 * 8, bhh, gi, N);
  }
  head_kernel<<<rowsState, 128, 0, stream>>>(hgb, hw, hb, (float*)d_out);
}